// Round 11
// baseline (663.054 us; speedup 1.0000x reference)
//
#include <hip/hip_runtime.h>
#include <hip/hip_bf16.h>

using bf16x8   = __attribute__((ext_vector_type(8))) __bf16;
using floatx4  = __attribute__((ext_vector_type(4))) float;
using floatx16 = __attribute__((ext_vector_type(16))) float;

#define DEVINL __device__ __forceinline__

DEVINL void gload16(const void* g, void* l) {
  __builtin_amdgcn_global_load_lds(
      (__attribute__((address_space(1))) void*)g,
      (__attribute__((address_space(3))) void*)l,
      16, 0, 0);
}

constexpr int S_ = 1024, D_ = 4096, HQ_ = 32, HKV_ = 8, HD_ = 128, B_ = 4;

// ---------------- convert x: fp32 -> bf16 ----------------
__global__ void conv_bf16(const float* __restrict__ in, __bf16* __restrict__ out, int n) {
  int i = (blockIdx.x * 256 + threadIdx.x) * 8;
  if (i >= n) return;
  float4 a = *(const float4*)(in + i);
  float4 b = *(const float4*)(in + i + 4);
  bf16x8 o;
  o[0] = (__bf16)a.x; o[1] = (__bf16)a.y; o[2] = (__bf16)a.z; o[3] = (__bf16)a.w;
  o[4] = (__bf16)b.x; o[5] = (__bf16)b.y; o[6] = (__bf16)b.z; o[7] = (__bf16)b.w;
  *(bf16x8*)(out + i) = o;
}

// ---------------- transpose+convert: W[K][N] fp32 -> WT[N][K] bf16, 64x64 vectorized ----------------
__global__ void conv_transpose(const float* __restrict__ W, __bf16* __restrict__ WT, int K, int N) {
  __shared__ float tile[64][65];
  const int n0 = blockIdx.x * 64, k0 = blockIdx.y * 64;
  const int rx = threadIdx.x & 15, ry = threadIdx.x >> 4;
#pragma unroll
  for (int i = 0; i < 64; i += 16) {
    float4 v = *(const float4*)&W[(size_t)(k0 + ry + i) * N + n0 + rx * 4];
    tile[ry + i][rx * 4 + 0] = v.x;
    tile[ry + i][rx * 4 + 1] = v.y;
    tile[ry + i][rx * 4 + 2] = v.z;
    tile[ry + i][rx * 4 + 3] = v.w;
  }
  __syncthreads();
  const int wx = threadIdx.x & 7, wy = threadIdx.x >> 3;
#pragma unroll
  for (int i = 0; i < 64; i += 32) {
    bf16x8 o;
#pragma unroll
    for (int j = 0; j < 8; j++) o[j] = (__bf16)tile[wx * 8 + j][wy + i];
    *(bf16x8*)&WT[(size_t)(n0 + wy + i) * K + k0 + wx * 8] = o;
  }
}

// ======== 256x256 gemm8p (r6 structure) + rectangular XCD partition ========
// Grid (24,16): XCD x owns a 6bx x 8by rectangle -> per-XCD panels 12MB B + 16MB A
// (vs 48MB B row-stripe before). orig%8 = XCD [m09].
__global__ __launch_bounds__(512, 1)
void gemm8p_qkv(const __bf16* __restrict__ A, const __bf16* __restrict__ BT,
                const float* __restrict__ b0, const float* __restrict__ b1,
                const float* __restrict__ b2, void* __restrict__ Cout,
                int M, int N, int K)
{
  __shared__ __bf16 lds[65536];  // 128 KB
  const int t = threadIdx.x;
  const int lane = t & 63, w = t >> 6;
  const int wm = w >> 2, wn = w & 3;
  const int g = (lane >> 4) & 3, c = lane & 15;

  // rect-XCD mapping: grid 24x16, rect 6x8, 4 col-groups x 2 row-groups
  const int orig = blockIdx.y * gridDim.x + blockIdx.x;
  const int xcd = orig & 7, i6 = orig >> 3;       // i6 in 0..47
  const int bx = (xcd & 3) * 6 + i6 % 6;
  const int by = (xcd >> 2) * 8 + i6 / 6;
  const int m0 = by * 256, n0 = bx * 256;

  const floatx4 zero4 = {0.f, 0.f, 0.f, 0.f};
  floatx4 acc[2][2][4][2];
#pragma unroll
  for (int a = 0; a < 2; a++)
#pragma unroll
    for (int bq = 0; bq < 2; bq++)
#pragma unroll
      for (int i = 0; i < 4; i++)
#pragma unroll
        for (int j = 0; j < 2; j++) acc[a][bq][i][j] = zero4;

  const int t3 = t >> 3;
  const int l8 = ((t & 7) ^ (t3 & 7)) * 8;
  const int browc = (t3 & 31) + ((t3 >> 5) << 6);
  const __bf16* srcA0 = A  + (size_t)(m0 + t3) * K + l8;
  const __bf16* srcA1 = A  + (size_t)(m0 + 64 + t3) * K + l8;
  const __bf16* srcB0 = BT + (size_t)(n0 + browc) * K + l8;
  const __bf16* srcB1 = BT + (size_t)(n0 + 32 + browc) * K + l8;
  const size_t k128 = (size_t)128 * K;

  const int arow_rd = (wm * 64 + c) * 64;
  const int brow_rd = (wn * 32 + c) * 64;
  const int sel0 = ((g) ^ (c & 7)) * 8;
  const int sel1 = ((4 + g) ^ (c & 7)) * 8;

  const int NT = K >> 6;

  bf16x8 af[4][2], bf0[2][2], bf1[2][2];

#define STG(srcp, subofs, kt, pbuf)                                              \
  gload16((srcp) + (size_t)(kt) * 64,        &lds[(pbuf) + (subofs) + t * 8]);   \
  gload16((srcp) + (size_t)(kt) * 64 + k128, &lds[(pbuf) + (subofs) + 4096 + t * 8]);

#define LOADA(MQ, bb)                                                            \
  _Pragma("unroll")                                                              \
  for (int i = 0; i < 4; i++) {                                                  \
    af[i][0] = *(const bf16x8*)&lds[(bb) + (MQ)*8192 + arow_rd + i*1024 + sel0]; \
    af[i][1] = *(const bf16x8*)&lds[(bb) + (MQ)*8192 + arow_rd + i*1024 + sel1]; \
  }

#define LOADB(DST, NQ, bb)                                                       \
  _Pragma("unroll")                                                              \
  for (int j = 0; j < 2; j++) {                                                  \
    DST[j][0] = *(const bf16x8*)&lds[(bb) + 16384 + (NQ)*8192 + brow_rd + j*1024 + sel0]; \
    DST[j][1] = *(const bf16x8*)&lds[(bb) + 16384 + (NQ)*8192 + brow_rd + j*1024 + sel1]; \
  }

#define MFMAQ(MQ, NQ, BF)                                                        \
  __builtin_amdgcn_s_setprio(1);                                                 \
  _Pragma("unroll")                                                              \
  for (int i = 0; i < 4; i++)                                                    \
    _Pragma("unroll")                                                            \
    for (int j = 0; j < 2; j++) {                                                \
      acc[MQ][NQ][i][j] = __builtin_amdgcn_mfma_f32_16x16x32_bf16(af[i][0], BF[j][0], acc[MQ][NQ][i][j], 0, 0, 0); \
      acc[MQ][NQ][i][j] = __builtin_amdgcn_mfma_f32_16x16x32_bf16(af[i][1], BF[j][1], acc[MQ][NQ][i][j], 0, 0, 0); \
    }                                                                            \
  __builtin_amdgcn_s_setprio(0);

#define SBAR() __builtin_amdgcn_sched_barrier(0)
#define BARR() __builtin_amdgcn_s_barrier()
#define VMC(N) asm volatile("s_waitcnt vmcnt(" #N ")" ::: "memory");
#define LGKM0() asm volatile("s_waitcnt lgkmcnt(0)" ::: "memory");

  STG(srcA0, 0, 0, 0)
  STG(srcB0, 16384, 0, 0)
  STG(srcB1, 24576, 0, 0)
  STG(srcA1, 8192, 0, 0)
  VMC(4) BARR(); SBAR();

  for (int v = 0; v < NT - 1; ++v) {
    const int bb = (v & 1) * 32768;
    const int nb = bb ^ 32768;
    LOADA(0, bb)
    LOADB(bf0, 0, bb)
    STG(srcA0, 0, v + 1, nb)
    SBAR(); VMC(4) BARR(); LGKM0() SBAR();
    MFMAQ(0, 0, bf0)
    SBAR(); BARR(); SBAR();
    LOADB(bf1, 1, bb)
    STG(srcB0, 16384, v + 1, nb)
    SBAR(); VMC(4) BARR(); LGKM0() SBAR();
    MFMAQ(0, 1, bf1)
    SBAR(); BARR(); SBAR();
    LOADA(1, bb)
    STG(srcB1, 24576, v + 1, nb)
    SBAR(); BARR(); LGKM0() SBAR();
    MFMAQ(1, 1, bf1)
    SBAR(); BARR(); SBAR();
    STG(srcA1, 8192, v + 1, nb)
    SBAR(); VMC(4) BARR(); SBAR();
    MFMAQ(1, 0, bf0)
    SBAR(); BARR(); SBAR();
  }
  {
    const int bb = ((NT - 1) & 1) * 32768;
    LOADA(0, bb)
    LOADB(bf0, 0, bb)
    SBAR(); VMC(2) BARR(); LGKM0() SBAR();
    MFMAQ(0, 0, bf0)
    SBAR(); BARR(); SBAR();
    LOADB(bf1, 1, bb)
    SBAR(); VMC(0) BARR(); LGKM0() SBAR();
    MFMAQ(0, 1, bf1)
    SBAR(); BARR(); SBAR();
    LOADA(1, bb)
    SBAR(); BARR(); LGKM0() SBAR();
    MFMAQ(1, 1, bf1)
    MFMAQ(1, 0, bf0)
  }

#undef STG
#undef LOADA
#undef LOADB
#undef MFMAQ
#undef SBAR
#undef BARR
#undef VMC
#undef LGKM0

#pragma unroll
  for (int mq = 0; mq < 2; mq++)
#pragma unroll
    for (int nq = 0; nq < 2; nq++)
#pragma unroll
      for (int j = 0; j < 2; j++) {
        const int ncol = n0 + wn * 64 + nq * 32 + j * 16 + c;
#pragma unroll
        for (int i = 0; i < 4; i++) {
          const int mbase = m0 + wm * 128 + mq * 64 + i * 16 + g * 4;
#pragma unroll
          for (int r = 0; r < 4; r++) {
            const int m = mbase + r;
            float v = acc[mq][nq][i][j][r];
            const int bb2 = m >> 10, s = m & 1023;
            __bf16* qkv = (__bf16*)Cout;
            if (ncol < 4096) {
              v += b0[ncol];
              const int h = ncol >> 7, d = ncol & 127;
              qkv[(((size_t)bb2 * 32 + h) * 1024 + s) * 128 + d] = (__bf16)v;
            } else if (ncol < 5120) {
              const int nc = ncol - 4096;
              v += b1[nc];
              const int h = nc >> 7, d = nc & 127;
              qkv[16777216 + (((size_t)bb2 * 8 + h) * 1024 + s) * 128 + d] = (__bf16)v;
            } else {
              const int nc = ncol - 5120;
              v += b2[nc];
              const int h = nc >> 7, d = nc & 127;
              qkv[20971520 + (((size_t)bb2 * 8 + h) * 128 + d) * 1024 + s] = (__bf16)v;
            }
          }
        }
      }
}

// ======== 128x128 gemm (r3 structure) + rectangular XCD partition ========
// Grid (32,32): XCD x owns a 16bx x 8by rectangle (16MB B + 8MB A per XCD).
__global__ __launch_bounds__(256, 2)
void gemm_oproj(const __bf16* __restrict__ A, const __bf16* __restrict__ BT,
                const float* __restrict__ bias, float* __restrict__ Cout,
                int M, int N, int K)
{
  __shared__ __bf16 Alds[4096];
  __shared__ __bf16 Blds[4096];
  const int t = threadIdx.x;
  const int lane = t & 63;
  const int w = t >> 6;
  const int wr = w >> 1, wc = w & 1;
  const int g = lane >> 4, c = lane & 15;

  // rect-XCD mapping: grid 32x32, rect 16x8, 2 col-groups x 4 row-groups
  const int orig = blockIdx.y * gridDim.x + blockIdx.x;
  const int xcd = orig & 7, i6 = orig >> 3;       // i6 in 0..127
  const int bx = (xcd & 1) * 16 + (i6 & 15);
  const int by = (xcd >> 1) * 8 + (i6 >> 4);
  const int m0 = by * 128, n0 = bx * 128;

  const floatx4 zero4 = {0.f, 0.f, 0.f, 0.f};
  floatx4 acc[4][4];
#pragma unroll
  for (int i = 0; i < 4; i++)
#pragma unroll
    for (int j = 0; j < 4; j++) acc[i][j] = zero4;

  const int srow = t >> 2;
  const int ga = (t & 3) ^ ((t >> 3) & 3);
  const __bf16* Ar = A  + (size_t)(m0 + srow) * K + ga * 8;
  const __bf16* Br = BT + (size_t)(n0 + srow) * K + ga * 8;
  const size_t rstep = (size_t)64 * K;

  const int sl = (g ^ ((c >> 1) & 3)) * 8;
  const int aoff = (wr * 64 + c) * 32 + sl;
  const int boff = (wc * 64 + c) * 32 + sl;

  for (int kt = 0; kt < K; kt += 32) {
    gload16(Ar + kt,         &Alds[t * 8]);
    gload16(Ar + rstep + kt, &Alds[(t + 256) * 8]);
    gload16(Br + kt,         &Blds[t * 8]);
    gload16(Br + rstep + kt, &Blds[(t + 256) * 8]);
    __syncthreads();
    bf16x8 af[4], bfr[4];
#pragma unroll
    for (int i = 0; i < 4; i++)
      af[i] = *(const bf16x8*)&Alds[aoff + i * 512];
#pragma unroll
    for (int j = 0; j < 4; j++)
      bfr[j] = *(const bf16x8*)&Blds[boff + j * 512];
#pragma unroll
    for (int i = 0; i < 4; i++)
#pragma unroll
      for (int j = 0; j < 4; j++)
        acc[i][j] = __builtin_amdgcn_mfma_f32_16x16x32_bf16(af[i], bfr[j], acc[i][j], 0, 0, 0);
    __syncthreads();
  }

#pragma unroll
  for (int j = 0; j < 4; j++) {
    const int ncol = n0 + wc * 64 + j * 16 + c;
    const float bv = bias[ncol];
#pragma unroll
    for (int i = 0; i < 4; i++) {
      const int mbase = m0 + wr * 64 + i * 16 + g * 4;
#pragma unroll
      for (int r = 0; r < 4; r++) {
        const int m = mbase + r;
        Cout[(size_t)m * N + ncol] = acc[i][j][r] + bv;
      }
    }
  }
}

// ---------------- RoPE in-place on q_t (b,h,s,d) and k_t ----------------
constexpr int NQCH = B_ * HQ_ * S_ * (HD_ / 8);
constexpr int NKCH = B_ * HKV_ * S_ * (HD_ / 8);
__global__ void rope_kernel(__bf16* __restrict__ qt, __bf16* __restrict__ kt,
                            const float* __restrict__ fc, const int* __restrict__ sp) {
  int tid = blockIdx.x * 256 + threadIdx.x;
  __bf16* p;
  int idx;
  if (tid < NQCH) { p = qt; idx = tid; }
  else { idx = tid - NQCH; if (idx >= NKCH) return; p = kt; }
  const int c8 = idx & 15;
  const int s  = (idx >> 4) & 1023;
  const int srow = sp[0] + s;
  const float* f = fc + (size_t)srow * 128 + c8 * 8;
  float4 fa = *(const float4*)(f);
  float4 fb = *(const float4*)(f + 4);
  __bf16* q = p + (size_t)idx * 8;
  bf16x8 v = *(const bf16x8*)q;
  float a0 = (float)v[0], b0 = (float)v[1], a1 = (float)v[2], b1 = (float)v[3];
  float a2 = (float)v[4], b2 = (float)v[5], a3 = (float)v[6], b3 = (float)v[7];
  bf16x8 o;
  o[0] = (__bf16)(a0 * fa.x - b0 * fa.y); o[1] = (__bf16)(a0 * fa.y + b0 * fa.x);
  o[2] = (__bf16)(a1 * fa.z - b1 * fa.w); o[3] = (__bf16)(a1 * fa.w + b1 * fa.z);
  o[4] = (__bf16)(a2 * fb.x - b2 * fb.y); o[5] = (__bf16)(a2 * fb.y + b2 * fb.x);
  o[6] = (__bf16)(a3 * fb.z - b3 * fb.w); o[7] = (__bf16)(a3 * fb.w + b3 * fb.z);
  *(bf16x8*)q = o;
}

// ---------------- flash attention: swapped-QK^T 32x32, K-prefetch pipeline ----------------
__global__ __launch_bounds__(256, 2)
void flash_attn(const __bf16* __restrict__ qt, const __bf16* __restrict__ kt,
                const __bf16* __restrict__ vt, __bf16* __restrict__ obuf)
{
  const int lane = threadIdx.x & 63, w = threadIdx.x >> 6;
  const int rl = lane & 31, hi = lane >> 5;
  const int qb = blockIdx.x & 7;
  const int bh = blockIdx.x >> 3;
  const int b = bh >> 5, h = bh & 31, hk = h >> 2;
  const int q0w = (qb + w * 8) * 32;

  const __bf16* Qp = qt + (size_t)(b * HQ_ + h) * S_ * HD_;
  const __bf16* Kp = kt + (size_t)(b * HKV_ + hk) * S_ * HD_;
  const __bf16* Vp = vt + (size_t)(b * HKV_ + hk) * HD_ * S_;  // V^T [d][s]

  const __bf16* Qb = Qp + (size_t)(q0w + rl) * HD_ + hi * 8;
  bf16x8 qf[8];
#pragma unroll
  for (int d = 0; d < 8; d++) qf[d] = *(const bf16x8*)(Qb + d * 16);

  const __bf16* Kb = Kp + (size_t)rl * HD_ + hi * 8;
  const __bf16* Vb = Vp + (size_t)rl * S_ + hi * 8;

  const floatx16 zero16 = {0.f,0.f,0.f,0.f,0.f,0.f,0.f,0.f,0.f,0.f,0.f,0.f,0.f,0.f,0.f,0.f};
  floatx16 oacc[4];
#pragma unroll
  for (int dt = 0; dt < 4; dt++) oacc[dt] = zero16;

  float m_run = -__builtin_inff();
  float l_run = 0.f;
  const float ksc = 0.12751744875895f;  // (1/sqrt(128)) * log2(e)

  bf16x8 kf[8], kn[8];
#pragma unroll
  for (int d = 0; d < 8; d++) kf[d] = *(const bf16x8*)(Kb + d * 16);

  for (int kv0 = 0; kv0 <= q0w; kv0 += 32) {
    bf16x8 vf[4][2];
#pragma unroll
    for (int dt = 0; dt < 4; dt++)
#pragma unroll
      for (int kh = 0; kh < 2; kh++)
        vf[dt][kh] = *(const bf16x8*)(Vb + (size_t)dt * 32 * S_ + kv0 + kh * 16);

    floatx16 acc = zero16;
#pragma unroll
    for (int d = 0; d < 8; d++)
      acc = __builtin_amdgcn_mfma_f32_32x32x16_bf16(kf[d], qf[d], acc, 0, 0, 0);

    const int kvn = (kv0 < q0w) ? kv0 + 32 : kv0;
#pragma unroll
    for (int d = 0; d < 8; d++)
      kn[d] = *(const bf16x8*)(Kb + (size_t)kvn * HD_ + d * 16);

    if (kv0 == q0w) {
#pragma unroll
      for (int r = 0; r < 16; r++) {
        const int krel = (r & 3) + 8 * (r >> 2) + 4 * hi;
        if (krel > rl) acc[r] = -3e29f;
      }
    }

    float mx = acc[0];
#pragma unroll
    for (int r = 1; r < 16; r++) mx = fmaxf(mx, acc[r]);
    mx = fmaxf(mx, __shfl_xor(mx, 32));
    const float m_cand = mx * ksc;

    float m_use;
    const bool defer = __all(m_cand - m_run <= 8.0f);
    if (defer) {
      m_use = m_run;
    } else {
      const float m_new = fmaxf(m_run, m_cand);
      const float alpha = exp2f(m_run - m_new);
      l_run *= alpha;
      float ar[16];
#pragma unroll
      for (int r = 0; r < 16; r++)
        ar[r] = __shfl(alpha, (r & 3) + 8 * (r >> 2) + 4 * hi);
#pragma unroll
      for (int dt = 0; dt < 4; dt++)
#pragma unroll
        for (int r = 0; r < 16; r++) oacc[dt][r] *= ar[r];
      m_run = m_new;
      m_use = m_new;
    }

    float pr[16];
#pragma unroll
    for (int r = 0; r < 16; r++) pr[r] = exp2f(fmaf(acc[r], ksc, -m_use));
    float rs = pr[0];
#pragma unroll
    for (int r = 1; r < 16; r++) rs += pr[r];
    rs += __shfl_xor(rs, 32);
    l_run += rs;

    bf16x8 pa[2];
#pragma unroll
    for (int kh = 0; kh < 2; kh++) {
      const int rb = kh * 8;
      unsigned a0, b0, a1, b1;
      asm("v_cvt_pk_bf16_f32 %0, %1, %2" : "=v"(a0) : "v"(pr[rb + 0]), "v"(pr[rb + 1]));
      asm("v_cvt_pk_bf16_f32 %0, %1, %2" : "=v"(b0) : "v"(pr[rb + 4]), "v"(pr[rb + 5]));
      asm("v_cvt_pk_bf16_f32 %0, %1, %2" : "=v"(a1) : "v"(pr[rb + 2]), "v"(pr[rb + 3]));
      asm("v_cvt_pk_bf16_f32 %0, %1, %2" : "=v"(b1) : "v"(pr[rb + 6]), "v"(pr[rb + 7]));
      asm("v_permlane32_swap_b32 %0, %1" : "+v"(a0), "+v"(b0));
      asm("v_permlane32_swap_b32 %0, %1" : "+v"(a1), "+v"(b1));
      union { unsigned u[4]; bf16x8 v; } cvt;
      cvt.u[0] = a0; cvt.u[1] = a1; cvt.u[2] = b0; cvt.u[3] = b1;
      pa[kh] = cvt.v;
    }

#pragma unroll
    for (int dt = 0; dt < 4; dt++) {
      oacc[dt] = __builtin_amdgcn_mfma_f32_32x32x16_bf16(pa[0], vf[dt][0], oacc[dt], 0, 0, 0);
      oacc[dt] = __builtin_amdgcn_mfma_f32_32x32x16_bf16(pa[1], vf[dt][1], oacc[dt], 0, 0, 0);
    }

#pragma unroll
    for (int d = 0; d < 8; d++) kf[d] = kn[d];
  }

  const float linv = 1.f / l_run;
  float lr[16];
#pragma unroll
  for (int r = 0; r < 16; r++)
    lr[r] = __shfl(linv, (r & 3) + 8 * (r >> 2) + 4 * hi);
#pragma unroll
  for (int dt = 0; dt < 4; dt++)
#pragma unroll
    for (int r = 0; r < 16; r++) {
      const int qrow = q0w + (r & 3) + 8 * (r >> 2) + 4 * hi;
      const size_t o = (size_t)(b * S_ + qrow) * D_ + h * HD_ + dt * 32 + rl;
      obuf[o] = (__bf16)(oacc[dt][r] * lr[r]);
    }
}

extern "C" void kernel_launch(void* const* d_in, const int* in_sizes, int n_in,
                              void* d_out, int out_size, void* d_ws, size_t ws_size,
                              hipStream_t stream) {
  (void)in_sizes; (void)n_in; (void)out_size;
  const float* x  = (const float*)d_in[0];
  const float* fc = (const float*)d_in[1];
  const float* Wq = (const float*)d_in[2];
  const float* bq = (const float*)d_in[3];
  const float* Wk = (const float*)d_in[4];
  const float* bk = (const float*)d_in[5];
  const float* Wv = (const float*)d_in[6];
  const float* bv = (const float*)d_in[7];
  const float* Wo = (const float*)d_in[8];
  const float* bo = (const float*)d_in[9];
  const int*   sp = (const int*)d_in[10];
  float* out = (float*)d_out;

  const size_t MB = 1024 * 1024;
  if (ws_size < 192 * MB) return;
  char* ws = (char*)d_ws;
  __bf16* xb     = (__bf16*)(ws + 0);        // 32 MB
  __bf16* WqkvT  = (__bf16*)(ws + 32 * MB);  // 48 MB: Wq^T | Wk^T | Wv^T  [6144][4096]
  __bf16* WoT    = (__bf16*)(ws + 80 * MB);  // 32 MB
  __bf16* q_t    = (__bf16*)(ws + 112 * MB); // 32 MB (b,h,s,d)
  __bf16* k_t    = (__bf16*)(ws + 144 * MB); //  8 MB (b,h,s,d)
  __bf16* v_t    = (__bf16*)(ws + 152 * MB); //  8 MB (b,h,d,s)
  __bf16* ob     = (__bf16*)(ws + 160 * MB); // 32 MB

  conv_bf16<<<8192, 256, 0, stream>>>(x, xb, D_ * B_ * S_);
  conv_transpose<<<dim3(64, 64), 256, 0, stream>>>(Wq, WqkvT, 4096, 4096);
  conv_transpose<<<dim3(16, 64), 256, 0, stream>>>(Wk, WqkvT + (size_t)4096 * 4096, 4096, 1024);
  conv_transpose<<<dim3(16, 64), 256, 0, stream>>>(Wv, WqkvT + (size_t)5120 * 4096, 4096, 1024);
  conv_transpose<<<dim3(64, 64), 256, 0, stream>>>(Wo, WoT, 4096, 4096);

  gemm8p_qkv<<<dim3(24, 16), 512, 0, stream>>>(xb, WqkvT, bq, bk, bv, q_t, 4096, 6144, 4096);

  rope_kernel<<<(NQCH + NKCH) / 256, 256, 0, stream>>>(q_t, k_t, fc, sp);
  flash_attn<<<1024, 256, 0, stream>>>(q_t, k_t, v_t, ob);

  gemm_oproj<<<dim3(32, 32), 256, 0, stream>>>(ob, WoT, bo, out, 4096, 4096, 4096);
}

// Round 12
// 645.536 us; speedup vs baseline: 1.0271x; 1.0271x over previous
//
#include <hip/hip_runtime.h>
#include <hip/hip_bf16.h>

using bf16x8   = __attribute__((ext_vector_type(8))) __bf16;
using floatx4  = __attribute__((ext_vector_type(4))) float;
using floatx16 = __attribute__((ext_vector_type(16))) float;

#define DEVINL __device__ __forceinline__

DEVINL void gload16(const void* g, void* l) {
  __builtin_amdgcn_global_load_lds(
      (__attribute__((address_space(1))) void*)g,
      (__attribute__((address_space(3))) void*)l,
      16, 0, 0);
}

constexpr int S_ = 1024, D_ = 4096, HQ_ = 32, HKV_ = 8, HD_ = 128, B_ = 4;

// ---------------- convert x: fp32 -> bf16 ----------------
__global__ void conv_bf16(const float* __restrict__ in, __bf16* __restrict__ out, int n) {
  int i = (blockIdx.x * 256 + threadIdx.x) * 8;
  if (i >= n) return;
  float4 a = *(const float4*)(in + i);
  float4 b = *(const float4*)(in + i + 4);
  bf16x8 o;
  o[0] = (__bf16)a.x; o[1] = (__bf16)a.y; o[2] = (__bf16)a.z; o[3] = (__bf16)a.w;
  o[4] = (__bf16)b.x; o[5] = (__bf16)b.y; o[6] = (__bf16)b.z; o[7] = (__bf16)b.w;
  *(bf16x8*)(out + i) = o;
}

// ---------------- transpose+convert: W[K][N] fp32 -> WT[N][K] bf16, 64x64 vectorized ----------------
__global__ void conv_transpose(const float* __restrict__ W, __bf16* __restrict__ WT, int K, int N) {
  __shared__ float tile[64][65];
  const int n0 = blockIdx.x * 64, k0 = blockIdx.y * 64;
  const int rx = threadIdx.x & 15, ry = threadIdx.x >> 4;
#pragma unroll
  for (int i = 0; i < 64; i += 16) {
    float4 v = *(const float4*)&W[(size_t)(k0 + ry + i) * N + n0 + rx * 4];
    tile[ry + i][rx * 4 + 0] = v.x;
    tile[ry + i][rx * 4 + 1] = v.y;
    tile[ry + i][rx * 4 + 2] = v.z;
    tile[ry + i][rx * 4 + 3] = v.w;
  }
  __syncthreads();
  const int wx = threadIdx.x & 7, wy = threadIdx.x >> 3;
#pragma unroll
  for (int i = 0; i < 64; i += 32) {
    bf16x8 o;
#pragma unroll
    for (int j = 0; j < 8; j++) o[j] = (__bf16)tile[wx * 8 + j][wy + i];
    *(bf16x8*)&WT[(size_t)(n0 + wy + i) * K + k0 + wx * 8] = o;
  }
}

// ======== 256x256 gemm8p (r6/r10 structure, row-stripe swizzle) + FUSED RoPE epilogue ========
__global__ __launch_bounds__(512, 1)
void gemm8p_qkv(const __bf16* __restrict__ A, const __bf16* __restrict__ BT,
                const float* __restrict__ b0, const float* __restrict__ b1,
                const float* __restrict__ b2, void* __restrict__ Cout,
                const float* __restrict__ fc, const int* __restrict__ sp,
                int M, int N, int K)
{
  __shared__ __bf16 lds[65536];  // 128 KB
  const int t = threadIdx.x;
  const int lane = t & 63, w = t >> 6;
  const int wm = w >> 2, wn = w & 3;
  const int g = (lane >> 4) & 3, c = lane & 15;

  // row-stripe XCD swizzle (r10 measured-best)
  const int gridX = gridDim.x;
  const int nwg = gridDim.x * gridDim.y;
  int lin = blockIdx.y * gridDim.x + blockIdx.x;
  lin = (lin & 7) * (nwg >> 3) + (lin >> 3);
  const int bx = lin % gridX, by = lin / gridX;
  const int m0 = by * 256, n0 = bx * 256;

  const floatx4 zero4 = {0.f, 0.f, 0.f, 0.f};
  floatx4 acc[2][2][4][2];
#pragma unroll
  for (int a = 0; a < 2; a++)
#pragma unroll
    for (int bq = 0; bq < 2; bq++)
#pragma unroll
      for (int i = 0; i < 4; i++)
#pragma unroll
        for (int j = 0; j < 2; j++) acc[a][bq][i][j] = zero4;

  const int t3 = t >> 3;
  const int l8 = ((t & 7) ^ (t3 & 7)) * 8;
  const int browc = (t3 & 31) + ((t3 >> 5) << 6);
  const __bf16* srcA0 = A  + (size_t)(m0 + t3) * K + l8;
  const __bf16* srcA1 = A  + (size_t)(m0 + 64 + t3) * K + l8;
  const __bf16* srcB0 = BT + (size_t)(n0 + browc) * K + l8;
  const __bf16* srcB1 = BT + (size_t)(n0 + 32 + browc) * K + l8;
  const size_t k128 = (size_t)128 * K;

  const int arow_rd = (wm * 64 + c) * 64;
  const int brow_rd = (wn * 32 + c) * 64;
  const int sel0 = ((g) ^ (c & 7)) * 8;
  const int sel1 = ((4 + g) ^ (c & 7)) * 8;

  const int NT = K >> 6;

  bf16x8 af[4][2], bf0[2][2], bf1[2][2];

#define STG(srcp, subofs, kt, pbuf)                                              \
  gload16((srcp) + (size_t)(kt) * 64,        &lds[(pbuf) + (subofs) + t * 8]);   \
  gload16((srcp) + (size_t)(kt) * 64 + k128, &lds[(pbuf) + (subofs) + 4096 + t * 8]);

#define LOADA(MQ, bb)                                                            \
  _Pragma("unroll")                                                              \
  for (int i = 0; i < 4; i++) {                                                  \
    af[i][0] = *(const bf16x8*)&lds[(bb) + (MQ)*8192 + arow_rd + i*1024 + sel0]; \
    af[i][1] = *(const bf16x8*)&lds[(bb) + (MQ)*8192 + arow_rd + i*1024 + sel1]; \
  }

#define LOADB(DST, NQ, bb)                                                       \
  _Pragma("unroll")                                                              \
  for (int j = 0; j < 2; j++) {                                                  \
    DST[j][0] = *(const bf16x8*)&lds[(bb) + 16384 + (NQ)*8192 + brow_rd + j*1024 + sel0]; \
    DST[j][1] = *(const bf16x8*)&lds[(bb) + 16384 + (NQ)*8192 + brow_rd + j*1024 + sel1]; \
  }

#define MFMAQ(MQ, NQ, BF)                                                        \
  __builtin_amdgcn_s_setprio(1);                                                 \
  _Pragma("unroll")                                                              \
  for (int i = 0; i < 4; i++)                                                    \
    _Pragma("unroll")                                                            \
    for (int j = 0; j < 2; j++) {                                                \
      acc[MQ][NQ][i][j] = __builtin_amdgcn_mfma_f32_16x16x32_bf16(af[i][0], BF[j][0], acc[MQ][NQ][i][j], 0, 0, 0); \
      acc[MQ][NQ][i][j] = __builtin_amdgcn_mfma_f32_16x16x32_bf16(af[i][1], BF[j][1], acc[MQ][NQ][i][j], 0, 0, 0); \
    }                                                                            \
  __builtin_amdgcn_s_setprio(0);

#define SBAR() __builtin_amdgcn_sched_barrier(0)
#define BARR() __builtin_amdgcn_s_barrier()
#define VMC(N) asm volatile("s_waitcnt vmcnt(" #N ")" ::: "memory");
#define LGKM0() asm volatile("s_waitcnt lgkmcnt(0)" ::: "memory");

  STG(srcA0, 0, 0, 0)
  STG(srcB0, 16384, 0, 0)
  STG(srcB1, 24576, 0, 0)
  STG(srcA1, 8192, 0, 0)
  VMC(4) BARR(); SBAR();

  for (int v = 0; v < NT - 1; ++v) {
    const int bb = (v & 1) * 32768;
    const int nb = bb ^ 32768;
    LOADA(0, bb)
    LOADB(bf0, 0, bb)
    STG(srcA0, 0, v + 1, nb)
    SBAR(); VMC(4) BARR(); LGKM0() SBAR();
    MFMAQ(0, 0, bf0)
    SBAR(); BARR(); SBAR();
    LOADB(bf1, 1, bb)
    STG(srcB0, 16384, v + 1, nb)
    SBAR(); VMC(4) BARR(); LGKM0() SBAR();
    MFMAQ(0, 1, bf1)
    SBAR(); BARR(); SBAR();
    LOADA(1, bb)
    STG(srcB1, 24576, v + 1, nb)
    SBAR(); BARR(); LGKM0() SBAR();
    MFMAQ(1, 1, bf1)
    SBAR(); BARR(); SBAR();
    STG(srcA1, 8192, v + 1, nb)
    SBAR(); VMC(4) BARR(); SBAR();
    MFMAQ(1, 0, bf0)
    SBAR(); BARR(); SBAR();
  }
  {
    const int bb = ((NT - 1) & 1) * 32768;
    LOADA(0, bb)
    LOADB(bf0, 0, bb)
    SBAR(); VMC(2) BARR(); LGKM0() SBAR();
    MFMAQ(0, 0, bf0)
    SBAR(); BARR(); SBAR();
    LOADB(bf1, 1, bb)
    SBAR(); VMC(0) BARR(); LGKM0() SBAR();
    MFMAQ(0, 1, bf1)
    SBAR(); BARR(); SBAR();
    LOADA(1, bb)
    SBAR(); BARR(); LGKM0() SBAR();
    MFMAQ(1, 1, bf1)
    MFMAQ(1, 0, bf0)
  }

#undef STG
#undef LOADA
#undef LOADB
#undef MFMAQ
#undef SBAR
#undef BARR
#undef VMC
#undef LGKM0

  // ---- fused epilogue: bias + RoPE (q,k) + permuted store
  const int sp0 = sp[0];
#pragma unroll
  for (int mq = 0; mq < 2; mq++)
#pragma unroll
    for (int nq = 0; nq < 2; nq++)
#pragma unroll
      for (int j = 0; j < 2; j++) {
        const int ncol = n0 + wn * 64 + nq * 32 + j * 16 + c;
#pragma unroll
        for (int i = 0; i < 4; i++) {
          const int mbase = m0 + wm * 128 + mq * 64 + i * 16 + g * 4;
#pragma unroll
          for (int r = 0; r < 4; r++) {
            const int m = mbase + r;
            const int bb2 = m >> 10, s = m & 1023;
            float v = acc[mq][nq][i][j][r];
            // bias by region
            if (ncol < 4096)       v += b0[ncol];
            else if (ncol < 5120)  v += b1[ncol - 4096];
            else                   v += b2[ncol - 5120];
            // rotary partner: lane c^1 holds column d^1 (all-lane uniform shuffle)
            const float vp = __shfl_xor(v, 1);
            __bf16* qkv = (__bf16*)Cout;
            if (ncol < 5120) {
              const int d = ncol & 127;
              const float* f = fc + (((size_t)(sp0 + s)) << 7) + (d & ~1);
              const float cs = f[0], sn = f[1];
              v = (d & 1) ? fmaf(vp, sn, v * cs) : fmaf(v, cs, -(vp * sn));
              if (ncol < 4096) {
                const int h = ncol >> 7;
                qkv[(((size_t)bb2 * 32 + h) * 1024 + s) * 128 + d] = (__bf16)v;
              } else {
                const int h = (ncol - 4096) >> 7;
                qkv[16777216 + (((size_t)bb2 * 8 + h) * 1024 + s) * 128 + d] = (__bf16)v;
              }
            } else {
              const int nc = ncol - 5120;
              const int h = nc >> 7, d = nc & 127;
              qkv[20971520 + (((size_t)bb2 * 8 + h) * 128 + d) * 1024 + s] = (__bf16)v;
            }
          }
        }
      }
}

// ======== 128x128 gemm (r3 structure) + rectangular XCD partition (r11) ========
__global__ __launch_bounds__(256, 2)
void gemm_oproj(const __bf16* __restrict__ A, const __bf16* __restrict__ BT,
                const float* __restrict__ bias, float* __restrict__ Cout,
                int M, int N, int K)
{
  __shared__ __bf16 Alds[4096];
  __shared__ __bf16 Blds[4096];
  const int t = threadIdx.x;
  const int lane = t & 63;
  const int w = t >> 6;
  const int wr = w >> 1, wc = w & 1;
  const int g = lane >> 4, c = lane & 15;

  // rect-XCD mapping: grid 32x32, rect 16x8
  const int orig = blockIdx.y * gridDim.x + blockIdx.x;
  const int xcd = orig & 7, i6 = orig >> 3;
  const int bx = (xcd & 1) * 16 + (i6 & 15);
  const int by = (xcd >> 1) * 8 + (i6 >> 4);
  const int m0 = by * 128, n0 = bx * 128;

  const floatx4 zero4 = {0.f, 0.f, 0.f, 0.f};
  floatx4 acc[4][4];
#pragma unroll
  for (int i = 0; i < 4; i++)
#pragma unroll
    for (int j = 0; j < 4; j++) acc[i][j] = zero4;

  const int srow = t >> 2;
  const int ga = (t & 3) ^ ((t >> 3) & 3);
  const __bf16* Ar = A  + (size_t)(m0 + srow) * K + ga * 8;
  const __bf16* Br = BT + (size_t)(n0 + srow) * K + ga * 8;
  const size_t rstep = (size_t)64 * K;

  const int sl = (g ^ ((c >> 1) & 3)) * 8;
  const int aoff = (wr * 64 + c) * 32 + sl;
  const int boff = (wc * 64 + c) * 32 + sl;

  for (int kt = 0; kt < K; kt += 32) {
    gload16(Ar + kt,         &Alds[t * 8]);
    gload16(Ar + rstep + kt, &Alds[(t + 256) * 8]);
    gload16(Br + kt,         &Blds[t * 8]);
    gload16(Br + rstep + kt, &Blds[(t + 256) * 8]);
    __syncthreads();
    bf16x8 af[4], bfr[4];
#pragma unroll
    for (int i = 0; i < 4; i++)
      af[i] = *(const bf16x8*)&Alds[aoff + i * 512];
#pragma unroll
    for (int j = 0; j < 4; j++)
      bfr[j] = *(const bf16x8*)&Blds[boff + j * 512];
#pragma unroll
    for (int i = 0; i < 4; i++)
#pragma unroll
      for (int j = 0; j < 4; j++)
        acc[i][j] = __builtin_amdgcn_mfma_f32_16x16x32_bf16(af[i], bfr[j], acc[i][j], 0, 0, 0);
    __syncthreads();
  }

#pragma unroll
  for (int j = 0; j < 4; j++) {
    const int ncol = n0 + wc * 64 + j * 16 + c;
    const float bv = bias[ncol];
#pragma unroll
    for (int i = 0; i < 4; i++) {
      const int mbase = m0 + wr * 64 + i * 16 + g * 4;
#pragma unroll
      for (int r = 0; r < 4; r++) {
        const int m = mbase + r;
        Cout[(size_t)m * N + ncol] = acc[i][j][r] + bv;
      }
    }
  }
}

// ---------------- flash attention: swapped-QK^T 32x32, K-prefetch pipeline ----------------
__global__ __launch_bounds__(256, 2)
void flash_attn(const __bf16* __restrict__ qt, const __bf16* __restrict__ kt,
                const __bf16* __restrict__ vt, __bf16* __restrict__ obuf)
{
  const int lane = threadIdx.x & 63, w = threadIdx.x >> 6;
  const int rl = lane & 31, hi = lane >> 5;
  const int qb = blockIdx.x & 7;
  const int bh = blockIdx.x >> 3;
  const int b = bh >> 5, h = bh & 31, hk = h >> 2;
  const int q0w = (qb + w * 8) * 32;

  const __bf16* Qp = qt + (size_t)(b * HQ_ + h) * S_ * HD_;
  const __bf16* Kp = kt + (size_t)(b * HKV_ + hk) * S_ * HD_;
  const __bf16* Vp = vt + (size_t)(b * HKV_ + hk) * HD_ * S_;  // V^T [d][s]

  const __bf16* Qb = Qp + (size_t)(q0w + rl) * HD_ + hi * 8;
  bf16x8 qf[8];
#pragma unroll
  for (int d = 0; d < 8; d++) qf[d] = *(const bf16x8*)(Qb + d * 16);

  const __bf16* Kb = Kp + (size_t)rl * HD_ + hi * 8;
  const __bf16* Vb = Vp + (size_t)rl * S_ + hi * 8;

  const floatx16 zero16 = {0.f,0.f,0.f,0.f,0.f,0.f,0.f,0.f,0.f,0.f,0.f,0.f,0.f,0.f,0.f,0.f};
  floatx16 oacc[4];
#pragma unroll
  for (int dt = 0; dt < 4; dt++) oacc[dt] = zero16;

  float m_run = -__builtin_inff();
  float l_run = 0.f;
  const float ksc = 0.12751744875895f;  // (1/sqrt(128)) * log2(e)

  bf16x8 kf[8], kn[8];
#pragma unroll
  for (int d = 0; d < 8; d++) kf[d] = *(const bf16x8*)(Kb + d * 16);

  for (int kv0 = 0; kv0 <= q0w; kv0 += 32) {
    bf16x8 vf[4][2];
#pragma unroll
    for (int dt = 0; dt < 4; dt++)
#pragma unroll
      for (int kh = 0; kh < 2; kh++)
        vf[dt][kh] = *(const bf16x8*)(Vb + (size_t)dt * 32 * S_ + kv0 + kh * 16);

    floatx16 acc = zero16;
#pragma unroll
    for (int d = 0; d < 8; d++)
      acc = __builtin_amdgcn_mfma_f32_32x32x16_bf16(kf[d], qf[d], acc, 0, 0, 0);

    const int kvn = (kv0 < q0w) ? kv0 + 32 : kv0;
#pragma unroll
    for (int d = 0; d < 8; d++)
      kn[d] = *(const bf16x8*)(Kb + (size_t)kvn * HD_ + d * 16);

    if (kv0 == q0w) {
#pragma unroll
      for (int r = 0; r < 16; r++) {
        const int krel = (r & 3) + 8 * (r >> 2) + 4 * hi;
        if (krel > rl) acc[r] = -3e29f;
      }
    }

    float mx = acc[0];
#pragma unroll
    for (int r = 1; r < 16; r++) mx = fmaxf(mx, acc[r]);
    mx = fmaxf(mx, __shfl_xor(mx, 32));
    const float m_cand = mx * ksc;

    float m_use;
    const bool defer = __all(m_cand - m_run <= 8.0f);
    if (defer) {
      m_use = m_run;
    } else {
      const float m_new = fmaxf(m_run, m_cand);
      const float alpha = exp2f(m_run - m_new);
      l_run *= alpha;
      float ar[16];
#pragma unroll
      for (int r = 0; r < 16; r++)
        ar[r] = __shfl(alpha, (r & 3) + 8 * (r >> 2) + 4 * hi);
#pragma unroll
      for (int dt = 0; dt < 4; dt++)
#pragma unroll
        for (int r = 0; r < 16; r++) oacc[dt][r] *= ar[r];
      m_run = m_new;
      m_use = m_new;
    }

    float pr[16];
#pragma unroll
    for (int r = 0; r < 16; r++) pr[r] = exp2f(fmaf(acc[r], ksc, -m_use));
    float rs = pr[0];
#pragma unroll
    for (int r = 1; r < 16; r++) rs += pr[r];
    rs += __shfl_xor(rs, 32);
    l_run += rs;

    bf16x8 pa[2];
#pragma unroll
    for (int kh = 0; kh < 2; kh++) {
      const int rb = kh * 8;
      unsigned a0, b0, a1, b1;
      asm("v_cvt_pk_bf16_f32 %0, %1, %2" : "=v"(a0) : "v"(pr[rb + 0]), "v"(pr[rb + 1]));
      asm("v_cvt_pk_bf16_f32 %0, %1, %2" : "=v"(b0) : "v"(pr[rb + 4]), "v"(pr[rb + 5]));
      asm("v_cvt_pk_bf16_f32 %0, %1, %2" : "=v"(a1) : "v"(pr[rb + 2]), "v"(pr[rb + 3]));
      asm("v_cvt_pk_bf16_f32 %0, %1, %2" : "=v"(b1) : "v"(pr[rb + 6]), "v"(pr[rb + 7]));
      asm("v_permlane32_swap_b32 %0, %1" : "+v"(a0), "+v"(b0));
      asm("v_permlane32_swap_b32 %0, %1" : "+v"(a1), "+v"(b1));
      union { unsigned u[4]; bf16x8 v; } cvt;
      cvt.u[0] = a0; cvt.u[1] = a1; cvt.u[2] = b0; cvt.u[3] = b1;
      pa[kh] = cvt.v;
    }

#pragma unroll
    for (int dt = 0; dt < 4; dt++) {
      oacc[dt] = __builtin_amdgcn_mfma_f32_32x32x16_bf16(pa[0], vf[dt][0], oacc[dt], 0, 0, 0);
      oacc[dt] = __builtin_amdgcn_mfma_f32_32x32x16_bf16(pa[1], vf[dt][1], oacc[dt], 0, 0, 0);
    }

#pragma unroll
    for (int d = 0; d < 8; d++) kf[d] = kn[d];
  }

  const float linv = 1.f / l_run;
  float lr[16];
#pragma unroll
  for (int r = 0; r < 16; r++)
    lr[r] = __shfl(linv, (r & 3) + 8 * (r >> 2) + 4 * hi);
#pragma unroll
  for (int dt = 0; dt < 4; dt++)
#pragma unroll
    for (int r = 0; r < 16; r++) {
      const int qrow = q0w + (r & 3) + 8 * (r >> 2) + 4 * hi;
      const size_t o = (size_t)(b * S_ + qrow) * D_ + h * HD_ + dt * 32 + rl;
      obuf[o] = (__bf16)(oacc[dt][r] * lr[r]);
    }
}

extern "C" void kernel_launch(void* const* d_in, const int* in_sizes, int n_in,
                              void* d_out, int out_size, void* d_ws, size_t ws_size,
                              hipStream_t stream) {
  (void)in_sizes; (void)n_in; (void)out_size;
  const float* x  = (const float*)d_in[0];
  const float* fc = (const float*)d_in[1];
  const float* Wq = (const float*)d_in[2];
  const float* bq = (const float*)d_in[3];
  const float* Wk = (const float*)d_in[4];
  const float* bk = (const float*)d_in[5];
  const float* Wv = (const float*)d_in[6];
  const float* bv = (const float*)d_in[7];
  const float* Wo = (const float*)d_in[8];
  const float* bo = (const float*)d_in[9];
  const int*   sp = (const int*)d_in[10];
  float* out = (float*)d_out;

  const size_t MB = 1024 * 1024;
  if (ws_size < 192 * MB) return;
  char* ws = (char*)d_ws;
  __bf16* xb     = (__bf16*)(ws + 0);        // 32 MB
  __bf16* WqkvT  = (__bf16*)(ws + 32 * MB);  // 48 MB: Wq^T | Wk^T | Wv^T  [6144][4096]
  __bf16* WoT    = (__bf16*)(ws + 80 * MB);  // 32 MB
  __bf16* q_t    = (__bf16*)(ws + 112 * MB); // 32 MB (b,h,s,d)  [rope'd]
  __bf16* k_t    = (__bf16*)(ws + 144 * MB); //  8 MB (b,h,s,d)  [rope'd]
  __bf16* v_t    = (__bf16*)(ws + 152 * MB); //  8 MB (b,h,d,s)
  __bf16* ob     = (__bf16*)(ws + 160 * MB); // 32 MB

  conv_bf16<<<8192, 256, 0, stream>>>(x, xb, D_ * B_ * S_);
  conv_transpose<<<dim3(64, 64), 256, 0, stream>>>(Wq, WqkvT, 4096, 4096);
  conv_transpose<<<dim3(16, 64), 256, 0, stream>>>(Wk, WqkvT + (size_t)4096 * 4096, 4096, 1024);
  conv_transpose<<<dim3(16, 64), 256, 0, stream>>>(Wv, WqkvT + (size_t)5120 * 4096, 4096, 1024);
  conv_transpose<<<dim3(64, 64), 256, 0, stream>>>(Wo, WoT, 4096, 4096);

  // fused QKV projection + bias + RoPE
  gemm8p_qkv<<<dim3(24, 16), 512, 0, stream>>>(xb, WqkvT, bq, bk, bv, q_t, fc, sp, 4096, 6144, 4096);

  flash_attn<<<1024, 256, 0, stream>>>(q_t, k_t, v_t, ob);

  gemm_oproj<<<dim3(32, 32), 256, 0, stream>>>(ob, WoT, bo, out, 4096, 4096, 4096);
}